// Round 2
// baseline (549.807 us; speedup 1.0000x reference)
//
#include <hip/hip_runtime.h>

// Problem constants
#define NT   365
#define NS   256
#define NH   256
#define NG   32
#define NR   16
#define HID  256
#define NX   38          // 6 + NG
#define M_   (NT*NS)     // 93440
#define TOUT (NT-NR+1)   // 350

typedef __attribute__((ext_vector_type(8))) short short8;
typedef __attribute__((ext_vector_type(4))) float floatx4;

__device__ __forceinline__ unsigned short f2bf(float f) {
    unsigned u = __float_as_uint(f);
    u = (u + 0x7FFFu + ((u >> 16) & 1u)) >> 16;   // RNE
    return (unsigned short)u;
}
__device__ __forceinline__ float bf2f(unsigned short u) {
    return __uint_as_float(((unsigned)u) << 16);
}
__device__ __forceinline__ float sigmoidf_(float x) { return 1.f / (1.f + __expf(-x)); }

// ---------------- k_pre: per-(t,s) snow partition coefficients ----------------
__global__ __launch_bounds__(256) void k_pre(const float* __restrict__ x,
                                             float* __restrict__ ps,
                                             float* __restrict__ plc,
                                             float* __restrict__ e2) {
    int m = blockIdx.x * 256 + threadIdx.x;     // exactly 93440
    float P  = x[m*6+0], E = x[m*6+1], T1 = x[m*6+2], T2 = x[m*6+3];
    float vf;
    if (T2 <= 0.f)      vf = 1.f;     // where(T2<=0) applied last -> highest priority
    else if (T1 >= 0.f) vf = 0.f;
    else {
        float ratio = (T1 + T2) / (T2 - T1);
        ratio = fminf(fmaxf(ratio, -1.f), 1.f);
        vf = acosf(ratio) * (1.f / 3.1415f);
    }
    ps[m]  = P * vf;
    plc[m] = P * (1.f - vf);
    e2[m]  = 2.f * E;
}

// ---------------- k_w2t: fcT_w2 [256][768] fp32 -> bf16 transposed [768][256] ----------------
__global__ __launch_bounds__(256) void k_w2t(const float* __restrict__ w2,
                                             unsigned short* __restrict__ w2t) {
    int i = blockIdx.x * 256 + threadIdx.x;     // 196608
    int k = i / 768, n = i % 768;
    w2t[n*256 + k] = f2bf(w2[i]);
}

// ---------------- k_fcW: per-site reservoir params ----------------
// par planes (each NS*NH): 0 kp, 1 ks, 2 kg, 3 gp, 4 gL, 5 qb, 6 ga
__global__ __launch_bounds__(256) void k_fcW(const float* __restrict__ xc,
                                             const float* __restrict__ w1, const float* __restrict__ b1,
                                             const float* __restrict__ w2, const float* __restrict__ b2,
                                             float* __restrict__ par) {
    int s = blockIdx.x, j = threadIdx.x;
    __shared__ float xs[NG];
    __shared__ float h1[HID];
    __shared__ float red[256];
    if (j < NG) xs[j] = xc[s*NG + j];
    __syncthreads();
    float acc = b1[j];
#pragma unroll
    for (int g = 0; g < NG; ++g) acc += xs[g] * w1[g*HID + j];
    h1[j] = tanhf(acc);
    __syncthreads();
    float o[7];
#pragma unroll
    for (int k = 0; k < 7; ++k) o[k] = b2[k*NH + j];
    for (int t = 0; t < HID; ++t) {
        float h = h1[t];
        const float* w2r = w2 + t*(NH*7);
#pragma unroll
        for (int k = 0; k < 7; ++k) o[k] += h * w2r[k*NH + j];
    }
    // softmax over j for o[6]
    red[j] = o[6]; __syncthreads();
    for (int st = 128; st > 0; st >>= 1) {
        if (j < st) red[j] = fmaxf(red[j], red[j+st]);
        __syncthreads();
    }
    float mx = red[0]; __syncthreads();
    float e = __expf(o[6] - mx);
    red[j] = e; __syncthreads();
    for (int st = 128; st > 0; st >>= 1) {
        if (j < st) red[j] += red[j+st];
        __syncthreads();
    }
    float ga = e / red[0];
    int idx = s*NH + j;
    par[0*65536 + idx] = sigmoidf_(o[0]);
    par[1*65536 + idx] = sigmoidf_(o[1]);
    par[2*65536 + idx] = 0.1f * sigmoidf_(o[2]);
    par[3*65536 + idx] = sigmoidf_(o[3]);
    par[4*65536 + idx] = __expf(2.f * o[4]);   // exp(w)^2
    par[5*65536 + idx] = fmaxf(o[5], 0.f);
    par[6*65536 + idx] = ga;
}

// ---------------- k_fcR: routing weights, softmax over NR ----------------
__global__ __launch_bounds__(256) void k_fcR(const float* __restrict__ xc,
                                             const float* __restrict__ w1, const float* __restrict__ b1,
                                             const float* __restrict__ w2, const float* __restrict__ b2,
                                             float* __restrict__ r_out) {
    int s0 = blockIdx.x * 4, j = threadIdx.x;
    __shared__ float xs[4][NG];
    __shared__ float h1[4][HID];
    __shared__ float buf[4096];
    if (j < 4*NG) xs[j >> 5][j & 31] = xc[s0*NG + j];
    __syncthreads();
#pragma unroll
    for (int si = 0; si < 4; ++si) {
        float acc = b1[j];
#pragma unroll
        for (int g = 0; g < NG; ++g) acc += xs[si][g] * w1[g*HID + j];
        h1[si][j] = tanhf(acc);
    }
    __syncthreads();
    float a[4][16];
#pragma unroll
    for (int si = 0; si < 4; ++si)
#pragma unroll
        for (int m = 0; m < 16; ++m) a[si][m] = b2[m*256 + j];
    for (int t = 0; t < HID; ++t) {
        const float* w2r = w2 + t*4096;
        float w[16];
#pragma unroll
        for (int m = 0; m < 16; ++m) w[m] = w2r[m*256 + j];
#pragma unroll
        for (int si = 0; si < 4; ++si) {
            float h = h1[si][t];
#pragma unroll
            for (int m = 0; m < 16; ++m) a[si][m] += h * w[m];
        }
    }
    for (int si = 0; si < 4; ++si) {
#pragma unroll
        for (int m = 0; m < 16; ++m) buf[m*256 + j] = fmaxf(a[si][m], 0.f);
        __syncthreads();
        float v[NR], mx = -1e30f;
#pragma unroll
        for (int rr = 0; rr < NR; ++rr) { v[rr] = buf[j*NR + rr]; mx = fmaxf(mx, v[rr]); }
        float ssum = 0.f;
#pragma unroll
        for (int rr = 0; rr < NR; ++rr) { v[rr] = __expf(v[rr] - mx); ssum += v[rr]; }
        float inv = 1.f / ssum;
#pragma unroll
        for (int rr = 0; rr < NR; ++rr) r_out[((s0 + si)*NH + j)*NR + rr] = v[rr] * inv;
        __syncthreads();
    }
}

// ---------------- k_fcT1: GEMM1 [M,38]@[38,256] + tanh -> bf16 ----------------
__global__ __launch_bounds__(256) void k_fcT1(const float* __restrict__ x, const float* __restrict__ xc,
                                              const float* __restrict__ w1, const float* __restrict__ b1,
                                              unsigned short* __restrict__ h1b) {
    int m0 = blockIdx.x * 32;
    int j = threadIdx.x;
    __shared__ float xs[32][NX + 2];
    for (int idx = j; idx < 32*NX; idx += 256) {
        int rr = idx / NX, c = idx % NX;
        int m = m0 + rr, s = m & (NS - 1);
        xs[rr][c] = (c < 6) ? x[m*6 + c] : xc[s*NG + (c - 6)];
    }
    __syncthreads();
    float acc[32];
    float b = b1[j];
#pragma unroll
    for (int rr = 0; rr < 32; ++rr) acc[rr] = b;
    for (int g = 0; g < NX; ++g) {
        float w = w1[g*HID + j];
#pragma unroll
        for (int rr = 0; rr < 32; ++rr) acc[rr] += xs[rr][g] * w;
    }
#pragma unroll
    for (int rr = 0; rr < 32; ++rr)
        h1b[(m0 + rr)*HID + j] = f2bf(tanhf(acc[rr]));
}

// ---------------- k_gemm2: bf16 MFMA GEMM [M,256]@[256,768] -> raw bf16 V[m][768] ----------------
__global__ __launch_bounds__(256) void k_gemm2(const unsigned short* __restrict__ h1b,
                                               const unsigned short* __restrict__ w2t,
                                               const float* __restrict__ b2,
                                               unsigned short* __restrict__ V) {
    int bm = blockIdx.x;            // 730
    int bn = blockIdx.y;            // 6
    int tid = threadIdx.x;
    int wave = tid >> 6, lane = tid & 63;
    __shared__ __align__(16) unsigned short As[128*32];
    __shared__ __align__(16) unsigned short Bs[128*32];
    floatx4 acc[4][4];
#pragma unroll
    for (int i = 0; i < 4; ++i)
#pragma unroll
        for (int jj = 0; jj < 4; ++jj) acc[i][jj] = (floatx4)(0.f);

    int m0 = bm*128, n0 = bn*128;
    int rA = tid >> 2;              // 0..63
    int cA = (tid & 3) * 8;         // 0,8,16,24
    int wm = (wave >> 1) * 64, wn = (wave & 1) * 64;
    int lr = lane & 15, lq = lane >> 4;

    for (int k0 = 0; k0 < 256; k0 += 32) {
        short8 a0  = *(const short8*)(h1b + (m0 + rA     )*256 + k0 + cA);
        short8 a1  = *(const short8*)(h1b + (m0 + rA + 64)*256 + k0 + cA);
        short8 bv0 = *(const short8*)(w2t + (n0 + rA     )*256 + k0 + cA);
        short8 bv1 = *(const short8*)(w2t + (n0 + rA + 64)*256 + k0 + cA);
        __syncthreads();
        *(short8*)(As + rA*32 + cA)        = a0;
        *(short8*)(As + (rA + 64)*32 + cA) = a1;
        *(short8*)(Bs + rA*32 + cA)        = bv0;
        *(short8*)(Bs + (rA + 64)*32 + cA) = bv1;
        __syncthreads();
        short8 af[4], bf[4];
#pragma unroll
        for (int i = 0; i < 4; ++i)
            af[i] = *(const short8*)(As + (wm + i*16 + lr)*32 + lq*8);
#pragma unroll
        for (int jj = 0; jj < 4; ++jj)
            bf[jj] = *(const short8*)(Bs + (wn + jj*16 + lr)*32 + lq*8);
#pragma unroll
        for (int i = 0; i < 4; ++i)
#pragma unroll
            for (int jj = 0; jj < 4; ++jj)
                acc[i][jj] = __builtin_amdgcn_mfma_f32_16x16x32_bf16(af[i], bf[jj], acc[i][jj], 0, 0, 0);
    }

#pragma unroll
    for (int jj = 0; jj < 4; ++jj) {
        int n_glob = n0 + wn + jj*16 + lr;
        float bias = b2[n_glob];
#pragma unroll
        for (int i = 0; i < 4; ++i) {
#pragma unroll
            for (int rr = 0; rr < 4; ++rr) {
                int m = m0 + wm + i*16 + lq*4 + rr;
                V[(size_t)m*768 + n_glob] = f2bf(acc[i][jj][rr] + bias);
            }
        }
    }
}

// ---------------- k_scanconv: fused sequential scan + 16-tap conv + ga-reduce ----------------
// one block per site s; thread = hidden unit h
__global__ __launch_bounds__(256) void k_scanconv(const unsigned short* __restrict__ V,
                                                  const float* __restrict__ ps,
                                                  const float* __restrict__ plc,
                                                  const float* __restrict__ e2,
                                                  const float* __restrict__ par,
                                                  const float* __restrict__ r,
                                                  float* __restrict__ out) {
    int s = blockIdx.x, h = threadIdx.x;
    int idx = s*NH + h;
    __shared__ float s_ps[NT], s_plc[NT], s_e2[NT];
    __shared__ float cbuf[16][257];
    __shared__ float pbuf[16][17];
    for (int t = h; t < NT; t += 256) {
        s_ps[t]  = ps[t*NS + s];
        s_plc[t] = plc[t*NS + s];
        s_e2[t]  = e2[t*NS + s];
    }
    float kp = par[idx], ks_ = par[65536+idx], kg = par[2*65536+idx],
          gp = par[3*65536+idx], gL = par[4*65536+idx], qb = par[5*65536+idx],
          ga = par[6*65536+idx];
    float rt[NR];
#pragma unroll
    for (int j = 0; j < NR; ++j) rt[j] = r[(size_t)idx*NR + j];
    __syncthreads();

    const unsigned short* vp = V + (size_t)s*768 + h;   // + t*NS*768
    float Sf = 0.f, Ss = 0.f, Sg = 0.f;
    float qwin[16];
#pragma unroll
    for (int j = 0; j < 16; ++j) qwin[j] = 0.f;

    unsigned short c0[16], c1[16], c2[16], p0[16], p1[16], p2[16];
#pragma unroll
    for (int j = 0; j < 16; ++j) {
        size_t o = (size_t)j * (NS*768);
        c0[j] = vp[o]; c1[j] = vp[o + 256]; c2[j] = vp[o + 512];
    }

    for (int blk = 0; blk < 23; ++blk) {
        int tbase = blk * 16;
        // prefetch next 16 timesteps
#pragma unroll
        for (int j = 0; j < 16; ++j) {
            int t = tbase + 16 + j;
            if (t < NT) {
                size_t o = (size_t)t * (NS*768);
                p0[j] = vp[o]; p1[j] = vp[o + 256]; p2[j] = vp[o + 512];
            }
        }
#pragma unroll
        for (int j = 0; j < 16; ++j) {
            int t = tbase + j;
            if (t < NT) {
                float v0 = bf2f(c0[j]), v1 = bf2f(c1[j]), v2 = bf2f(c2[j]);
                float vi = fminf(fmaxf(v0 * (1.f/3.f) + 0.5f, 0.f), 1.f);
                float pl = s_plc[t] * vi;
                float ev = s_e2[t] * fmaxf(v1, 0.f);
                float fm = __expf(v2);
                float fs = s_ps[t];
                float qf = fminf(Sf + fs, fm);
                Sf = fmaxf(Sf + fs - fm, 0.f);
                float H = fmaxf(Ss + pl + qf - ev, 0.f);
                float qp = fmaxf(kp * (H - gL), 0.f);
                float qsa = ks_ * fminf(H, gL);
                Ss = H - qp - qsa;
                float qsg = qsa * gp;
                float qs = qsa - qsg;
                float qg = kg * (Sg + qsg) + qb;
                Sg = (1.f - kg) * (Sg + qsg) - qb;
                float q = qp + qs + qg;
                qwin[j] = q;                      // slot t & 15 == j (tbase multiple of 16)
                if (t >= 15) {
                    // y[t-15] = sum_k rt[k] * q[t-15+k]; q[t-15+k] at slot (j+1+k)&15
                    float c = 0.f;
#pragma unroll
                    for (int k = 0; k < 16; ++k) c += rt[k] * qwin[(j + 1 + k) & 15];
                    cbuf[j][h] = ga * c;
                }
            }
        }
#pragma unroll
        for (int j = 0; j < 16; ++j) { c0[j] = p0[j]; c1[j] = p1[j]; c2[j] = p2[j]; }

        __syncthreads();
        {   // phase 1: 16 threads per row
            int row = h >> 4, kk = h & 15;
            int tout_row = tbase + row - 15;
            if (tout_row >= 0 && tout_row < TOUT) {
                float p = 0.f;
#pragma unroll
                for (int i = 0; i < 16; ++i) p += cbuf[row][kk + 16*i];
                pbuf[row][kk] = p;
            }
        }
        __syncthreads();
        if (h < 16) {
            int tout = tbase + h - 15;
            if (tout >= 0 && tout < TOUT) {
                float y = 0.f;
#pragma unroll
                for (int k = 0; k < 16; ++k) y += pbuf[h][k];
                out[tout*NS + s] = y;
            }
        }
        // next block's cbuf writes are safe: phase1 finished before 2nd barrier;
        // next pbuf writes happen after next block's 1st barrier, after phase2 here.
    }
}

// ---------------- launch ----------------
extern "C" void kernel_launch(void* const* d_in, const int* in_sizes, int n_in,
                              void* d_out, int out_size, void* d_ws, size_t ws_size,
                              hipStream_t stream) {
    const float* x   = (const float*)d_in[0];
    const float* xc  = (const float*)d_in[1];
    const float* fw1 = (const float*)d_in[2];
    const float* fb1 = (const float*)d_in[3];
    const float* fw2 = (const float*)d_in[4];
    const float* fb2 = (const float*)d_in[5];
    const float* tw1 = (const float*)d_in[6];
    const float* tb1 = (const float*)d_in[7];
    const float* tw2 = (const float*)d_in[8];
    const float* tb2 = (const float*)d_in[9];
    const float* rw1 = (const float*)d_in[10];
    const float* rb1 = (const float*)d_in[11];
    const float* rw2 = (const float*)d_in[12];
    const float* rb2 = (const float*)d_in[13];
    float* out = (float*)d_out;
    char* ws = (char*)d_ws;

    // workspace layout (bytes, all 16-aligned); peak = 198,908,928 B (~190 MB)
    constexpr size_t OFF_PS   = 0;                        //   373,760
    constexpr size_t OFF_PLC  = 373760;                   //   373,760
    constexpr size_t OFF_E2   = 747520;                   //   373,760
    constexpr size_t OFF_PAR  = 1121280;                  // 1,835,008
    constexpr size_t OFF_R    = 2956288;                  // 4,194,304
    constexpr size_t OFF_W2T  = 7150592;                  //   393,216
    constexpr size_t OFF_H1B  = 7543808;                  // 47,841,280
    constexpr size_t OFF_V    = 55385088;                 // 143,523,840 -> end 198,908,928

    float* ps   = (float*)(ws + OFF_PS);
    float* plc  = (float*)(ws + OFF_PLC);
    float* e2   = (float*)(ws + OFF_E2);
    float* par  = (float*)(ws + OFF_PAR);
    float* rbuf = (float*)(ws + OFF_R);
    unsigned short* w2t = (unsigned short*)(ws + OFF_W2T);
    unsigned short* h1b = (unsigned short*)(ws + OFF_H1B);
    unsigned short* V   = (unsigned short*)(ws + OFF_V);

    k_pre     <<<M_/256, 256, 0, stream>>>(x, ps, plc, e2);
    k_w2t     <<<(HID*768)/256, 256, 0, stream>>>(tw2, w2t);
    k_fcW     <<<NS, 256, 0, stream>>>(xc, fw1, fb1, fw2, fb2, par);
    k_fcR     <<<NS/4, 256, 0, stream>>>(xc, rw1, rb1, rw2, rb2, rbuf);
    k_fcT1    <<<M_/32, 256, 0, stream>>>(x, xc, tw1, tb1, h1b);
    k_gemm2   <<<dim3(M_/128, 6), 256, 0, stream>>>(h1b, w2t, tb2, V);
    k_scanconv<<<NS, 256, 0, stream>>>(V, ps, plc, e2, par, rbuf, out);
}